// Round 7
// baseline (326.133 us; speedup 1.0000x reference)
//
#include <hip/hip_runtime.h>
#include <hip/hip_bf16.h>
#include <hip/hip_fp16.h>
#include <stdint.h>
#include <math.h>

// ---------------------------------------------------------------------------
// AttentionLayer: Q=XWq+bq, K=XWk+bk, V=XWv+bv; O = softmax(QK^T) V
// B=4, N=2048, D=1024. fp32 I/O; internals fp16, accumulation fp32.
// R7: algebraic fold of Q/K projections. S = QK^T = X·M·X^T + 1·c^T + rowconst
// with M = Wq·Wk^T, c = X·(Wk·bq); rowconst cancels in softmax. So only
// Z = X·M^T and V = X·Wv+bv are projected (one fused GEMM, N=2048), qk uses
// BT = Xh directly, and the K buffer vanishes. 189 -> 172 GF total.
// ---------------------------------------------------------------------------

typedef unsigned short ushort_t;
typedef __attribute__((ext_vector_type(8))) _Float16  f16x8;
typedef __attribute__((ext_vector_type(4))) _Float16  f16x4;
typedef __attribute__((ext_vector_type(4))) float     f32x4;

__device__ __forceinline__ void async_load16(const void* g, void* l) {
  __builtin_amdgcn_global_load_lds(
      (const __attribute__((address_space(1))) void*)g,
      (__attribute__((address_space(3))) void*)l, 16, 0, 0);
}

// ---------------------------------------------------------------------------
// ZV GEMM: A = Xh [M][1024], BT = [Mt | Wvt] [2048][1024].
// blockIdx.x<8: Z = X·M^T (plain fp16 store); >=8: V = X·Wv+bv stored
// transposed Vt[b][e][m]. Swizzled LDS, 2 BK=32 steps per barrier pair.
// ---------------------------------------------------------------------------
__global__ __launch_bounds__(256)
void zv_gemm_kernel(const ushort_t* __restrict__ A, const ushort_t* __restrict__ BT,
                    const float* __restrict__ bvp,
                    __half* __restrict__ Zh, ushort_t* __restrict__ Vt)
{
  const int K = 1024;
  __shared__ ushort_t As[2][128 * 32];
  __shared__ ushort_t Bs[2][128 * 32];

  const int t    = threadIdx.x;
  const int lane = t & 63;
  const int wave = t >> 6;
  const int wm   = (wave >> 1) * 64;
  const int wn   = (wave & 1) * 64;

  const ushort_t* Ab = A + (long)blockIdx.y * 128 * K;
  const ushort_t* Bb = BT + (long)blockIdx.x * 128 * K;

  const int ldr = t >> 2;
  const int swzs = (ldr & 3) ^ ((ldr >> 2) & 3);
  const int ldc = ((t & 3) ^ swzs) * 8;
  const int frow = lane & 15;
  const int fsz  = (frow & 3) ^ ((frow >> 2) & 3);
  const int fo   = (((lane >> 4) ^ fsz)) * 8;

  f32x4 acc[4][4];
  const f32x4 zero = {0.0f, 0.0f, 0.0f, 0.0f};
#pragma unroll
  for (int i = 0; i < 4; ++i)
#pragma unroll
    for (int j = 0; j < 4; ++j) acc[i][j] = zero;

  for (int k0 = 0; k0 < K; k0 += 64) {
    __syncthreads();
    const ushort_t* ga = Ab + (long)ldr * K + k0 + ldc;
    const ushort_t* gb = Bb + (long)ldr * K + k0 + ldc;
#pragma unroll
    for (int h = 0; h < 2; ++h) {
      async_load16(ga + h * 32,                &As[h][t * 8]);
      async_load16(ga + h * 32 + 64 * (long)K, &As[h][2048 + t * 8]);
      async_load16(gb + h * 32,                &Bs[h][t * 8]);
      async_load16(gb + h * 32 + 64 * (long)K, &Bs[h][2048 + t * 8]);
    }
    __syncthreads();
#pragma unroll
    for (int h = 0; h < 2; ++h) {
      f16x8 af[4], bf[4];
#pragma unroll
      for (int i = 0; i < 4; ++i) {
        af[i] = *(const f16x8*)&As[h][(wm + i * 16 + frow) * 32 + fo];
        bf[i] = *(const f16x8*)&Bs[h][(wn + i * 16 + frow) * 32 + fo];
      }
#pragma unroll
      for (int mi = 0; mi < 4; ++mi)
#pragma unroll
        for (int ni = 0; ni < 4; ++ni)
          acc[mi][ni] = __builtin_amdgcn_mfma_f32_16x16x32_f16(af[mi], bf[ni], acc[mi][ni], 0, 0, 0);
    }
  }

  const int er = (lane >> 4) * 4;
  const int ec = lane & 15;
  const int tgt = blockIdx.x >> 3;  // 0: Z, 1: V (block-uniform)
#pragma unroll
  for (int ni = 0; ni < 4; ++ni) {
    const int c = (blockIdx.x & 7) * 128 + wn + ni * 16 + ec;  // 0..1023
#pragma unroll
    for (int mi = 0; mi < 4; ++mi) {
      const long grow0 = (long)blockIdx.y * 128 + wm + mi * 16 + er;
      if (tgt == 0) {
#pragma unroll
        for (int r = 0; r < 4; ++r)
          Zh[(grow0 + r) * 1024 + c] = __float2half(acc[mi][ni][r]);
      } else {
        const float bval = bvp[c];
        const long b  = grow0 >> 11;       // batch (2048 rows per batch)
        const long ml = grow0 & 2047;
        f16x4 v4;
#pragma unroll
        for (int r = 0; r < 4; ++r) v4[r] = (_Float16)(acc[mi][ni][r] + bval);
        *(f16x4*)&Vt[b * 2097152 + (long)c * 2048 + ml] = v4;
      }
    }
  }
}

// ---------------------------------------------------------------------------
// Small fp16-out GEMM for Mt = Wk·Wq^T (C[d'][d] = sum_e Wk[d',e]Wq[d,e]).
// Grid (8,8), K=1024, N=1024.
// ---------------------------------------------------------------------------
__global__ __launch_bounds__(256)
void gemm_f16_kernel(const ushort_t* __restrict__ A, const ushort_t* __restrict__ BT,
                     __half* __restrict__ C)
{
  const int K = 1024;
  __shared__ ushort_t As[2][128 * 32];
  __shared__ ushort_t Bs[2][128 * 32];

  const int t    = threadIdx.x;
  const int lane = t & 63;
  const int wave = t >> 6;
  const int wm   = (wave >> 1) * 64;
  const int wn   = (wave & 1) * 64;

  const ushort_t* Ab = A + (long)blockIdx.y * 128 * K;
  const ushort_t* Bb = BT + (long)blockIdx.x * 128 * K;

  const int ldr = t >> 2;
  const int swzs = (ldr & 3) ^ ((ldr >> 2) & 3);
  const int ldc = ((t & 3) ^ swzs) * 8;
  const int frow = lane & 15;
  const int fsz  = (frow & 3) ^ ((frow >> 2) & 3);
  const int fo   = (((lane >> 4) ^ fsz)) * 8;

  f32x4 acc[4][4];
  const f32x4 zero = {0.0f, 0.0f, 0.0f, 0.0f};
#pragma unroll
  for (int i = 0; i < 4; ++i)
#pragma unroll
    for (int j = 0; j < 4; ++j) acc[i][j] = zero;

  for (int k0 = 0; k0 < K; k0 += 64) {
    __syncthreads();
    const ushort_t* ga = Ab + (long)ldr * K + k0 + ldc;
    const ushort_t* gb = Bb + (long)ldr * K + k0 + ldc;
#pragma unroll
    for (int h = 0; h < 2; ++h) {
      async_load16(ga + h * 32,                &As[h][t * 8]);
      async_load16(ga + h * 32 + 64 * (long)K, &As[h][2048 + t * 8]);
      async_load16(gb + h * 32,                &Bs[h][t * 8]);
      async_load16(gb + h * 32 + 64 * (long)K, &Bs[h][2048 + t * 8]);
    }
    __syncthreads();
#pragma unroll
    for (int h = 0; h < 2; ++h) {
      f16x8 af[4], bf[4];
#pragma unroll
      for (int i = 0; i < 4; ++i) {
        af[i] = *(const f16x8*)&As[h][(wm + i * 16 + frow) * 32 + fo];
        bf[i] = *(const f16x8*)&Bs[h][(wn + i * 16 + frow) * 32 + fo];
      }
#pragma unroll
      for (int mi = 0; mi < 4; ++mi)
#pragma unroll
        for (int ni = 0; ni < 4; ++ni)
          acc[mi][ni] = __builtin_amdgcn_mfma_f32_16x16x32_f16(af[mi], bf[ni], acc[mi][ni], 0, 0, 0);
    }
  }

  const int er = (lane >> 4) * 4;
  const int ec = lane & 15;
#pragma unroll
  for (int ni = 0; ni < 4; ++ni) {
    const int gcol = blockIdx.x * 128 + wn + ni * 16 + ec;
#pragma unroll
    for (int mi = 0; mi < 4; ++mi)
#pragma unroll
      for (int r = 0; r < 4; ++r) {
        const long grow = (long)blockIdx.y * 128 + wm + mi * 16 + er + r;
        C[grow * 1024 + gcol] = __float2half(acc[mi][ni][r]);
      }
  }
}

// ---------------------------------------------------------------------------
// QK^T (= Z·X^T + 1·c^T) with fused partial softmax, 64-col chunk stats.
// S[row][col] = exp(s - m_chunk) fp16; PM/PS[z][32][2048]. Grid (16,16,B).
// ---------------------------------------------------------------------------
__global__ __launch_bounds__(256)
void qk_gemm_kernel(const ushort_t* __restrict__ Z, const ushort_t* __restrict__ Xh,
                    const float* __restrict__ Cc,
                    __half* __restrict__ S, float* __restrict__ PM, float* __restrict__ PS)
{
  const int K = 1024;
  __shared__ ushort_t As[2][128 * 32];
  __shared__ ushort_t Bs[2][128 * 32];

  const int t    = threadIdx.x;
  const int lane = t & 63;
  const int wave = t >> 6;
  const int wm   = (wave >> 1) * 64;
  const int wn   = (wave & 1) * 64;
  const long z   = blockIdx.z;

  const ushort_t* Ab = Z + z * 2048 * 1024 + (long)blockIdx.y * 128 * K;
  const ushort_t* Bb = Xh + z * 2048 * 1024 + (long)blockIdx.x * 128 * K;
  __half* Sb = S + z * 2048 * 2048;

  const int ldr = t >> 2;
  const int swzs = (ldr & 3) ^ ((ldr >> 2) & 3);
  const int ldc = ((t & 3) ^ swzs) * 8;
  const int frow = lane & 15;
  const int fsz  = (frow & 3) ^ ((frow >> 2) & 3);
  const int fo   = (((lane >> 4) ^ fsz)) * 8;

  f32x4 acc[4][4];
  const f32x4 zero = {0.0f, 0.0f, 0.0f, 0.0f};
#pragma unroll
  for (int i = 0; i < 4; ++i)
#pragma unroll
    for (int j = 0; j < 4; ++j) acc[i][j] = zero;

  for (int k0 = 0; k0 < K; k0 += 64) {
    __syncthreads();
    const ushort_t* ga = Ab + (long)ldr * K + k0 + ldc;
    const ushort_t* gb = Bb + (long)ldr * K + k0 + ldc;
#pragma unroll
    for (int h = 0; h < 2; ++h) {
      async_load16(ga + h * 32,                &As[h][t * 8]);
      async_load16(ga + h * 32 + 64 * (long)K, &As[h][2048 + t * 8]);
      async_load16(gb + h * 32,                &Bs[h][t * 8]);
      async_load16(gb + h * 32 + 64 * (long)K, &Bs[h][2048 + t * 8]);
    }
    __syncthreads();
#pragma unroll
    for (int h = 0; h < 2; ++h) {
      f16x8 af[4], bf[4];
#pragma unroll
      for (int i = 0; i < 4; ++i) {
        af[i] = *(const f16x8*)&As[h][(wm + i * 16 + frow) * 32 + fo];
        bf[i] = *(const f16x8*)&Bs[h][(wn + i * 16 + frow) * 32 + fo];
      }
#pragma unroll
      for (int mi = 0; mi < 4; ++mi)
#pragma unroll
        for (int ni = 0; ni < 4; ++ni)
          acc[mi][ni] = __builtin_amdgcn_mfma_f32_16x16x32_f16(af[mi], bf[ni], acc[mi][ni], 0, 0, 0);
    }
  }

  const int er = (lane >> 4) * 4;
  const int ec = lane & 15;

  // add column bias c_m (the X·Wk·bq softmax-surviving term)
  const float* Ccb = Cc + z * 2048;
#pragma unroll
  for (int ni = 0; ni < 4; ++ni) {
    const float cbv = Ccb[blockIdx.x * 128 + wn + ni * 16 + ec];
#pragma unroll
    for (int mi = 0; mi < 4; ++mi)
#pragma unroll
      for (int r = 0; r < 4; ++r) acc[mi][ni][r] += cbv;
  }

  // per-64-col-chunk row max/expsum; this wave owns chunk cc.
  const int cc = blockIdx.x * 2 + (wave & 1);   // 0..31
  float* PMb = PM + z * 32 * 2048 + (long)cc * 2048;
  float* PSb = PS + z * 32 * 2048 + (long)cc * 2048;

#pragma unroll
  for (int mi = 0; mi < 4; ++mi)
#pragma unroll
    for (int r = 0; r < 4; ++r) {
      float m = fmaxf(fmaxf(acc[mi][0][r], acc[mi][1][r]),
                      fmaxf(acc[mi][2][r], acc[mi][3][r]));
      m = fmaxf(m, __shfl_xor(m, 1));
      m = fmaxf(m, __shfl_xor(m, 2));
      m = fmaxf(m, __shfl_xor(m, 4));
      m = fmaxf(m, __shfl_xor(m, 8));
      float s = 0.0f;
#pragma unroll
      for (int ni = 0; ni < 4; ++ni) {
        const float e = __expf(acc[mi][ni][r] - m);
        acc[mi][ni][r] = e;
        s += e;
      }
      s += __shfl_xor(s, 1);
      s += __shfl_xor(s, 2);
      s += __shfl_xor(s, 4);
      s += __shfl_xor(s, 8);
      if (ec == 0) {
        const long row = (long)blockIdx.y * 128 + wm + mi * 16 + er + r;
        PMb[row] = m;
        PSb[row] = s;
      }
    }

#pragma unroll
  for (int ni = 0; ni < 4; ++ni) {
    const long col = (long)blockIdx.x * 128 + wn + ni * 16 + ec;
#pragma unroll
    for (int mi = 0; mi < 4; ++mi)
#pragma unroll
      for (int r = 0; r < 4; ++r) {
        const long grow = (long)blockIdx.y * 128 + wm + mi * 16 + er + r;
        Sb[grow * 2048 + col] = __float2half(acc[mi][ni][r]);
      }
  }
}

// ---------------------------------------------------------------------------
// Fold 32 chunk partials into per-(row,chunk) scale = exp(pm-m)/l.
// ---------------------------------------------------------------------------
__global__ __launch_bounds__(256)
void softmax_reduce_kernel(const float* __restrict__ PM, const float* __restrict__ PS,
                           float* __restrict__ Sc)
{
  const int r = blockIdx.x * 256 + threadIdx.x;
  const int b = r >> 11, row = r & 2047;
  const long base = (long)b * 32 * 2048 + row;
  float m = -3.4e38f;
#pragma unroll
  for (int cb = 0; cb < 32; ++cb) m = fmaxf(m, PM[base + cb * 2048]);
  float l = 0.0f;
#pragma unroll
  for (int cb = 0; cb < 32; ++cb) l += PS[base + cb * 2048] * __expf(PM[base + cb * 2048] - m);
  const float inv = 1.0f / l;
#pragma unroll
  for (int cb = 0; cb < 32; ++cb) Sc[base + cb * 2048] = __expf(PM[base + cb * 2048] - m) * inv;
}

// ---------------------------------------------------------------------------
// PV: Out[m][e] = sum_k (S[m][k]*scale[m][k>>6]) * Vt[e][k]. Grid (8,16,B).
// ---------------------------------------------------------------------------
__global__ __launch_bounds__(256)
void pv_gemm_kernel(const ushort_t* __restrict__ S, const ushort_t* __restrict__ Vt,
                    const float* __restrict__ Sc, float* __restrict__ Out)
{
  const int K = 2048;
  __shared__ ushort_t As[2][128 * 32];
  __shared__ ushort_t Bs[2][128 * 32];

  const int t    = threadIdx.x;
  const int lane = t & 63;
  const int wave = t >> 6;
  const int wm   = (wave >> 1) * 64;
  const int wn   = (wave & 1) * 64;
  const long z   = blockIdx.z;

  const ushort_t* Ab = S + z * 2048 * 2048 + (long)blockIdx.y * 128 * K;
  const ushort_t* Bb = Vt + z * 1024 * 2048 + (long)blockIdx.x * 128 * K;
  const float* Scb = Sc + z * 32 * 2048;
  float* Cb = Out + z * 2048 * 1024;

  const int ldr = t >> 2;
  const int swzs = (ldr & 3) ^ ((ldr >> 2) & 3);
  const int ldc = ((t & 3) ^ swzs) * 8;
  const int frow = lane & 15;
  const int fsz  = (frow & 3) ^ ((frow >> 2) & 3);
  const int fo   = (((lane >> 4) ^ fsz)) * 8;

  const int arow0 = blockIdx.y * 128 + wm + frow;

  f32x4 acc[4][4];
  const f32x4 zero = {0.0f, 0.0f, 0.0f, 0.0f};
#pragma unroll
  for (int i = 0; i < 4; ++i)
#pragma unroll
    for (int j = 0; j < 4; ++j) acc[i][j] = zero;

  for (int k0 = 0; k0 < K; k0 += 64) {
    const int cb = k0 >> 6;
    _Float16 sc16[4];
#pragma unroll
    for (int i = 0; i < 4; ++i)
      sc16[i] = (_Float16)Scb[(long)cb * 2048 + arow0 + i * 16];

    __syncthreads();
    const ushort_t* ga = Ab + (long)ldr * K + k0 + ldc;
    const ushort_t* gb = Bb + (long)ldr * K + k0 + ldc;
#pragma unroll
    for (int h = 0; h < 2; ++h) {
      async_load16(ga + h * 32,                &As[h][t * 8]);
      async_load16(ga + h * 32 + 64 * (long)K, &As[h][2048 + t * 8]);
      async_load16(gb + h * 32,                &Bs[h][t * 8]);
      async_load16(gb + h * 32 + 64 * (long)K, &Bs[h][2048 + t * 8]);
    }
    __syncthreads();
#pragma unroll
    for (int h = 0; h < 2; ++h) {
      f16x8 af[4], bf[4];
#pragma unroll
      for (int i = 0; i < 4; ++i) {
        af[i] = *(const f16x8*)&As[h][(wm + i * 16 + frow) * 32 + fo] * sc16[i];
        bf[i] = *(const f16x8*)&Bs[h][(wn + i * 16 + frow) * 32 + fo];
      }
#pragma unroll
      for (int mi = 0; mi < 4; ++mi)
#pragma unroll
        for (int ni = 0; ni < 4; ++ni)
          acc[mi][ni] = __builtin_amdgcn_mfma_f32_16x16x32_f16(af[mi], bf[ni], acc[mi][ni], 0, 0, 0);
    }
  }

  const int er = (lane >> 4) * 4;
  const int ec = lane & 15;
#pragma unroll
  for (int ni = 0; ni < 4; ++ni) {
    const int gcol = blockIdx.x * 128 + wn + ni * 16 + ec;
#pragma unroll
    for (int mi = 0; mi < 4; ++mi) {
#pragma unroll
      for (int r = 0; r < 4; ++r) {
        const long grow = (long)blockIdx.y * 128 + wm + mi * 16 + er + r;
        Cb[grow * 1024 + gcol] = acc[mi][ni][r];
      }
    }
  }
}

// ---------------------------------------------------------------------------
// Combined prep: straight cvt X->Xh (nx blocks), Wq->Wqh (512), Wk->Wkh (512),
// then Wv transpose-cvt -> Wvt (1024 tile blocks). Grid = nx + 2048.
// ---------------------------------------------------------------------------
__global__ __launch_bounds__(256)
void prep_kernel(const float* __restrict__ X, __half* __restrict__ Xh, int nx,
                 const float* __restrict__ Wq, __half* __restrict__ Wqh,
                 const float* __restrict__ Wk, __half* __restrict__ Wkh,
                 const float* __restrict__ Wv, __half* __restrict__ Wvt)
{
  const int bid = blockIdx.x;
  const int tid = threadIdx.x;
  if (bid < nx + 1024) {
    const float* src; __half* dst; long base;
    if (bid < nx)          { src = X;  dst = Xh;  base = (long)bid * 2048; }
    else if (bid < nx+512) { src = Wq; dst = Wqh; base = (long)(bid - nx) * 2048; }
    else                   { src = Wk; dst = Wkh; base = (long)(bid - nx - 512) * 2048; }
    const long i = base + (long)tid * 8;
    const float4 a = *(const float4*)(src + i);
    const float4 b = *(const float4*)(src + i + 4);
    f16x8 h;
    h[0] = (_Float16)a.x; h[1] = (_Float16)a.y; h[2] = (_Float16)a.z; h[3] = (_Float16)a.w;
    h[4] = (_Float16)b.x; h[5] = (_Float16)b.y; h[6] = (_Float16)b.z; h[7] = (_Float16)b.w;
    *(f16x8*)((ushort_t*)dst + i) = h;
  } else {
    __shared__ float tile[32][33];
    const int t2 = bid - (nx + 1024);
    const int c0 = (t2 & 31) * 32;
    const int r0 = (t2 >> 5) * 32;
    const int tx = tid & 31;
    const int ty = tid >> 5;
#pragma unroll
    for (int i = 0; i < 32; i += 8)
      tile[ty + i][tx] = Wv[(long)(r0 + ty + i) * 1024 + (c0 + tx)];
    __syncthreads();
#pragma unroll
    for (int i = 0; i < 32; i += 8)
      Wvt[(long)(c0 + ty + i) * 1024 + (r0 + tx)] = __float2half(tile[tx][ty + i]);
  }
}

// ---------------------------------------------------------------------------
// fp32 -> fp16 elementwise (fallback path only).
// ---------------------------------------------------------------------------
__global__ __launch_bounds__(256)
void cvt_f32_f16_kernel(const float* __restrict__ src, __half* __restrict__ dst, long n)
{
  const long i = ((long)blockIdx.x * 256 + threadIdx.x) * 8;
  if (i + 8 > n) return;
  const float4 a = *(const float4*)(src + i);
  const float4 b = *(const float4*)(src + i + 4);
  f16x8 h;
  h[0] = (_Float16)a.x; h[1] = (_Float16)a.y; h[2] = (_Float16)a.z; h[3] = (_Float16)a.w;
  h[4] = (_Float16)b.x; h[5] = (_Float16)b.y; h[6] = (_Float16)b.z; h[7] = (_Float16)b.w;
  *(f16x8*)((ushort_t*)dst + i) = h;
}

// ---------------------------------------------------------------------------
// wkbq[d] = sum_e Wk[d][e] * bq[e]  (fp32). Grid 4 x 256.
// ---------------------------------------------------------------------------
__global__ __launch_bounds__(256)
void wkbq_kernel(const float* __restrict__ Wk, const float* __restrict__ bq,
                 float* __restrict__ wkbq)
{
  const int d = blockIdx.x * 256 + threadIdx.x;
  const float* row = Wk + (long)d * 1024;
  float acc = 0.0f;
  for (int e = 0; e < 1024; e += 4) {
    const float4 wv = *(const float4*)(row + e);
    const float4 bv = *(const float4*)(bq + e);
    acc += wv.x * bv.x + wv.y * bv.y + wv.z * bv.z + wv.w * bv.w;
  }
  wkbq[d] = acc;
}

// ---------------------------------------------------------------------------
// c[row] = sum_d Xh[row][d] * wkbq[d]. One wave per row; grid = rows/4.
// ---------------------------------------------------------------------------
__global__ __launch_bounds__(256)
void cgemv_kernel(const ushort_t* __restrict__ Xh, const float* __restrict__ wkbq,
                  float* __restrict__ c)
{
  const int wave = threadIdx.x >> 6, lane = threadIdx.x & 63;
  const long row = (long)blockIdx.x * 4 + wave;
  const ushort_t* xr = Xh + row * 1024 + lane * 16;
  const f16x8 a0 = *(const f16x8*)xr;
  const f16x8 a1 = *(const f16x8*)(xr + 8);
  const float* wb = wkbq + lane * 16;
  float acc = 0.0f;
#pragma unroll
  for (int j = 0; j < 8; ++j) acc += (float)a0[j] * wb[j];
#pragma unroll
  for (int j = 0; j < 8; ++j) acc += (float)a1[j] * wb[j + 8];
#pragma unroll
  for (int off = 32; off > 0; off >>= 1) acc += __shfl_xor(acc, off, 64);
  if (lane == 0) c[row] = acc;
}

// ---------------------------------------------------------------------------
extern "C" void kernel_launch(void* const* d_in, const int* in_sizes, int n_in,
                              void* d_out, int out_size, void* d_ws, size_t ws_size,
                              hipStream_t stream)
{
  const int  Bb = 4, Nn = 2048, Dd = 1024;
  const long BN = (long)Bb * Nn;  // 8192

  const float* X  = (const float*)d_in[0];
  const float* Wq = (const float*)d_in[1];
  const float* bq = (const float*)d_in[2];
  const float* Wk = (const float*)d_in[3];
  const float* bk = (const float*)d_in[4];  (void)bk;  // cancels in softmax
  const float* Wv = (const float*)d_in[5];
  const float* bv = (const float*)d_in[6];
  float* Out      = (float*)d_out;

  uint8_t* w = (uint8_t*)d_ws;
  ushort_t* Wqh   = (ushort_t*)w;  w += (size_t)Dd * Dd * 2;
  ushort_t* Wkh   = (ushort_t*)w;  w += (size_t)Dd * Dd * 2;
  ushort_t* MtWvt = (ushort_t*)w;  w += (size_t)2 * Dd * Dd * 2;  // [Mt | Wvt]
  ushort_t* Mt  = MtWvt;
  ushort_t* Wvt = MtWvt + (size_t)Dd * Dd;
  float* wkbq = (float*)w;  w += (size_t)Dd * 4;
  float* cvec = (float*)w;  w += (size_t)BN * 4;

  const size_t statsBytes = (size_t)Bb * 32 * Nn * 4;
  const size_t fullNeed = (size_t)8 * Dd * Dd * 2 + Dd * 4 + BN * 4
                        + 3 * ((size_t)BN * Dd * 2)      // Xh, Zh, Vt
                        + (size_t)Bb * Nn * Nn * 2       // S fp16
                        + 3 * statsBytes;

  // wkbq depends only on raw fp32 inputs -> launch first
  wkbq_kernel<<<dim3(Dd / 256), 256, 0, stream>>>(Wk, bq, wkbq);

  if (ws_size >= fullNeed) {
    ushort_t* Xh = (ushort_t*)w;  w += (size_t)BN * Dd * 2;
    ushort_t* Zh = (ushort_t*)w;  w += (size_t)BN * Dd * 2;
    ushort_t* Vt = (ushort_t*)w;  w += (size_t)BN * Dd * 2;  // [B][Dd][Nn]
    ushort_t* S  = (ushort_t*)w;  w += (size_t)Bb * Nn * Nn * 2;
    float*    PM = (float*)w;     w += statsBytes;
    float*    PS = (float*)w;     w += statsBytes;
    float*    Sc = (float*)w;

    const int nx = (int)(BN * Dd / 2048);  // 4096
    prep_kernel<<<dim3(nx + 2048), 256, 0, stream>>>(
        X, (__half*)Xh, nx, Wq, (__half*)Wqh, Wk, (__half*)Wkh, Wv, (__half*)Wvt);

    // Mt[d'][d] = sum_e Wk[d'][e] Wq[d][e]  (= M^T, the BT operand for Z)
    gemm_f16_kernel<<<dim3(Dd / 128, Dd / 128), 256, 0, stream>>>(Wkh, Wqh, (__half*)Mt);

    // c = Xh . wkbq  per row (all batches)
    cgemv_kernel<<<dim3((unsigned)(BN / 4)), 256, 0, stream>>>(Xh, wkbq, cvec);

    // Z = X M^T ; V = X Wv + bv (transposed store)
    zv_gemm_kernel<<<dim3(2 * Dd / 128, BN / 128), 256, 0, stream>>>(
        Xh, MtWvt, bv, (__half*)Zh, Vt);

    // S = Z X^T + 1 c^T, fused partial softmax
    qk_gemm_kernel<<<dim3(Nn / 128, Nn / 128, Bb), 256, 0, stream>>>(
        Zh, Xh, cvec, (__half*)S, PM, PS);

    softmax_reduce_kernel<<<dim3((unsigned)(Bb * Nn / 256)), 256, 0, stream>>>(PM, PS, Sc);

    pv_gemm_kernel<<<dim3(Dd / 128, Nn / 128, Bb), 256, 0, stream>>>(S, Vt, Sc, Out);
  } else {
    // Per-batch fallback (~30 MB ws)
    ushort_t* Xh = (ushort_t*)w;  w += (size_t)Nn * Dd * 2;
    ushort_t* Zh = (ushort_t*)w;  w += (size_t)Nn * Dd * 2;
    ushort_t* Vt = (ushort_t*)w;  w += (size_t)Nn * Dd * 2;
    ushort_t* S  = (ushort_t*)w;  w += (size_t)Nn * Nn * 2;
    float*    PM = (float*)w;     w += (size_t)32 * Nn * 4;
    float*    PS = (float*)w;     w += (size_t)32 * Nn * 4;
    float*    Sc = (float*)w;

    prep_kernel<<<dim3(2048), 256, 0, stream>>>(
        nullptr, nullptr, 0, Wq, (__half*)Wqh, Wk, (__half*)Wkh, Wv, (__half*)Wvt);
    gemm_f16_kernel<<<dim3(Dd / 128, Dd / 128), 256, 0, stream>>>(Wkh, Wqh, (__half*)Mt);

    for (int b = 0; b < Bb; ++b) {
      const float* Xb = X + (long)b * Nn * Dd;
      cvt_f32_f16_kernel<<<dim3((unsigned)((long)Nn * Dd / (8 * 256))), 256, 0, stream>>>(
          Xb, (__half*)Xh, (long)Nn * Dd);
      cgemv_kernel<<<dim3(Nn / 4), 256, 0, stream>>>(Xh, wkbq, cvec);
      zv_gemm_kernel<<<dim3(2 * Dd / 128, Nn / 128), 256, 0, stream>>>(
          Xh, MtWvt, bv, (__half*)Zh, Vt);
      qk_gemm_kernel<<<dim3(Nn / 128, Nn / 128, 1), 256, 0, stream>>>(
          Zh, Xh, cvec, (__half*)S, PM, PS);
      softmax_reduce_kernel<<<dim3(Nn / 256), 256, 0, stream>>>(PM, PS, Sc);
      pv_gemm_kernel<<<dim3(Dd / 128, Nn / 128, 1), 256, 0, stream>>>(
          S, Vt, Sc, Out + (long)b * Nn * Dd);
    }
  }
}

// Round 8
// 285.777 us; speedup vs baseline: 1.1412x; 1.1412x over previous
//
#include <hip/hip_runtime.h>
#include <hip/hip_bf16.h>
#include <hip/hip_fp16.h>
#include <stdint.h>
#include <math.h>

// ---------------------------------------------------------------------------
// AttentionLayer: Q=XWq+bq, K=XWk+bk, V=XWv+bv; O = softmax(QK^T) V
// B=4, N=2048, D=1024. fp32 I/O; internals fp16, accumulation fp32.
// R8: R7 algebra (S = X·M·X^T + 1·c^T, M=Wq·Wk^T, rowconst cancels) with the
// serial small-kernel overhead removed: c folds into Z as a column bias
// (Z' = X·M^T + 1·wkbq^T, wkbq = Wk·bq), so cgemv/cvec/qk-bias are gone and
// wkbq runs on a proper 256-block grid (R7's 4-block GEMV was ~25% of the
// regression; grid must saturate 256 CUs).
// ---------------------------------------------------------------------------

typedef unsigned short ushort_t;
typedef __attribute__((ext_vector_type(8))) _Float16  f16x8;
typedef __attribute__((ext_vector_type(4))) _Float16  f16x4;
typedef __attribute__((ext_vector_type(4))) float     f32x4;

__device__ __forceinline__ void async_load16(const void* g, void* l) {
  __builtin_amdgcn_global_load_lds(
      (const __attribute__((address_space(1))) void*)g,
      (__attribute__((address_space(3))) void*)l, 16, 0, 0);
}

// ---------------------------------------------------------------------------
// ZV GEMM: A = Xh [M][1024], BT = [Mt | Wvt] [2048][1024].
// blockIdx.x<8: Z' = X·M^T + wkbq (fp16 store); >=8: V = X·Wv+bv stored
// transposed Vt[b][e][m]. Swizzled LDS, 2 BK=32 steps per barrier pair.
// ---------------------------------------------------------------------------
__global__ __launch_bounds__(256)
void zv_gemm_kernel(const ushort_t* __restrict__ A, const ushort_t* __restrict__ BT,
                    const float* __restrict__ wkbq, const float* __restrict__ bvp,
                    __half* __restrict__ Zh, ushort_t* __restrict__ Vt)
{
  const int K = 1024;
  __shared__ ushort_t As[2][128 * 32];
  __shared__ ushort_t Bs[2][128 * 32];

  const int t    = threadIdx.x;
  const int lane = t & 63;
  const int wave = t >> 6;
  const int wm   = (wave >> 1) * 64;
  const int wn   = (wave & 1) * 64;

  const ushort_t* Ab = A + (long)blockIdx.y * 128 * K;
  const ushort_t* Bb = BT + (long)blockIdx.x * 128 * K;

  const int ldr = t >> 2;
  const int swzs = (ldr & 3) ^ ((ldr >> 2) & 3);
  const int ldc = ((t & 3) ^ swzs) * 8;
  const int frow = lane & 15;
  const int fsz  = (frow & 3) ^ ((frow >> 2) & 3);
  const int fo   = (((lane >> 4) ^ fsz)) * 8;

  f32x4 acc[4][4];
  const f32x4 zero = {0.0f, 0.0f, 0.0f, 0.0f};
#pragma unroll
  for (int i = 0; i < 4; ++i)
#pragma unroll
    for (int j = 0; j < 4; ++j) acc[i][j] = zero;

  for (int k0 = 0; k0 < K; k0 += 64) {
    __syncthreads();
    const ushort_t* ga = Ab + (long)ldr * K + k0 + ldc;
    const ushort_t* gb = Bb + (long)ldr * K + k0 + ldc;
#pragma unroll
    for (int h = 0; h < 2; ++h) {
      async_load16(ga + h * 32,                &As[h][t * 8]);
      async_load16(ga + h * 32 + 64 * (long)K, &As[h][2048 + t * 8]);
      async_load16(gb + h * 32,                &Bs[h][t * 8]);
      async_load16(gb + h * 32 + 64 * (long)K, &Bs[h][2048 + t * 8]);
    }
    __syncthreads();
#pragma unroll
    for (int h = 0; h < 2; ++h) {
      f16x8 af[4], bf[4];
#pragma unroll
      for (int i = 0; i < 4; ++i) {
        af[i] = *(const f16x8*)&As[h][(wm + i * 16 + frow) * 32 + fo];
        bf[i] = *(const f16x8*)&Bs[h][(wn + i * 16 + frow) * 32 + fo];
      }
#pragma unroll
      for (int mi = 0; mi < 4; ++mi)
#pragma unroll
        for (int ni = 0; ni < 4; ++ni)
          acc[mi][ni] = __builtin_amdgcn_mfma_f32_16x16x32_f16(af[mi], bf[ni], acc[mi][ni], 0, 0, 0);
    }
  }

  const int er = (lane >> 4) * 4;
  const int ec = lane & 15;
  const int tgt = blockIdx.x >> 3;  // 0: Z, 1: V (block-uniform)
#pragma unroll
  for (int ni = 0; ni < 4; ++ni) {
    const int c = (blockIdx.x & 7) * 128 + wn + ni * 16 + ec;  // 0..1023
    const float bval = (tgt == 0) ? wkbq[c] : bvp[c];
#pragma unroll
    for (int mi = 0; mi < 4; ++mi) {
      const long grow0 = (long)blockIdx.y * 128 + wm + mi * 16 + er;
      if (tgt == 0) {
#pragma unroll
        for (int r = 0; r < 4; ++r)
          Zh[(grow0 + r) * 1024 + c] = __float2half(acc[mi][ni][r] + bval);
      } else {
        const long b  = grow0 >> 11;       // batch (2048 rows per batch)
        const long ml = grow0 & 2047;
        f16x4 v4;
#pragma unroll
        for (int r = 0; r < 4; ++r) v4[r] = (_Float16)(acc[mi][ni][r] + bval);
        *(f16x4*)&Vt[b * 2097152 + (long)c * 2048 + ml] = v4;
      }
    }
  }
}

// ---------------------------------------------------------------------------
// Small fp16-out GEMM for Mt = Wk·Wq^T (C[d'][d] = sum_e Wk[d',e]Wq[d,e]).
// Grid (8,8), K=1024.
// ---------------------------------------------------------------------------
__global__ __launch_bounds__(256)
void gemm_f16_kernel(const ushort_t* __restrict__ A, const ushort_t* __restrict__ BT,
                     __half* __restrict__ C)
{
  const int K = 1024;
  __shared__ ushort_t As[2][128 * 32];
  __shared__ ushort_t Bs[2][128 * 32];

  const int t    = threadIdx.x;
  const int lane = t & 63;
  const int wave = t >> 6;
  const int wm   = (wave >> 1) * 64;
  const int wn   = (wave & 1) * 64;

  const ushort_t* Ab = A + (long)blockIdx.y * 128 * K;
  const ushort_t* Bb = BT + (long)blockIdx.x * 128 * K;

  const int ldr = t >> 2;
  const int swzs = (ldr & 3) ^ ((ldr >> 2) & 3);
  const int ldc = ((t & 3) ^ swzs) * 8;
  const int frow = lane & 15;
  const int fsz  = (frow & 3) ^ ((frow >> 2) & 3);
  const int fo   = (((lane >> 4) ^ fsz)) * 8;

  f32x4 acc[4][4];
  const f32x4 zero = {0.0f, 0.0f, 0.0f, 0.0f};
#pragma unroll
  for (int i = 0; i < 4; ++i)
#pragma unroll
    for (int j = 0; j < 4; ++j) acc[i][j] = zero;

  for (int k0 = 0; k0 < K; k0 += 64) {
    __syncthreads();
    const ushort_t* ga = Ab + (long)ldr * K + k0 + ldc;
    const ushort_t* gb = Bb + (long)ldr * K + k0 + ldc;
#pragma unroll
    for (int h = 0; h < 2; ++h) {
      async_load16(ga + h * 32,                &As[h][t * 8]);
      async_load16(ga + h * 32 + 64 * (long)K, &As[h][2048 + t * 8]);
      async_load16(gb + h * 32,                &Bs[h][t * 8]);
      async_load16(gb + h * 32 + 64 * (long)K, &Bs[h][2048 + t * 8]);
    }
    __syncthreads();
#pragma unroll
    for (int h = 0; h < 2; ++h) {
      f16x8 af[4], bf[4];
#pragma unroll
      for (int i = 0; i < 4; ++i) {
        af[i] = *(const f16x8*)&As[h][(wm + i * 16 + frow) * 32 + fo];
        bf[i] = *(const f16x8*)&Bs[h][(wn + i * 16 + frow) * 32 + fo];
      }
#pragma unroll
      for (int mi = 0; mi < 4; ++mi)
#pragma unroll
        for (int ni = 0; ni < 4; ++ni)
          acc[mi][ni] = __builtin_amdgcn_mfma_f32_16x16x32_f16(af[mi], bf[ni], acc[mi][ni], 0, 0, 0);
    }
  }

  const int er = (lane >> 4) * 4;
  const int ec = lane & 15;
#pragma unroll
  for (int ni = 0; ni < 4; ++ni) {
    const int gcol = blockIdx.x * 128 + wn + ni * 16 + ec;
#pragma unroll
    for (int mi = 0; mi < 4; ++mi)
#pragma unroll
      for (int r = 0; r < 4; ++r) {
        const long grow = (long)blockIdx.y * 128 + wm + mi * 16 + er + r;
        C[grow * 1024 + gcol] = __float2half(acc[mi][ni][r]);
      }
  }
}

// ---------------------------------------------------------------------------
// S = Z'·X^T with fused partial softmax, 64-col chunk stats.
// S[row][col] = exp(s - m_chunk) fp16; PM/PS[z][32][2048]. Grid (16,16,B).
// ---------------------------------------------------------------------------
__global__ __launch_bounds__(256)
void qk_gemm_kernel(const ushort_t* __restrict__ Z, const ushort_t* __restrict__ Xh,
                    __half* __restrict__ S, float* __restrict__ PM, float* __restrict__ PS)
{
  const int K = 1024;
  __shared__ ushort_t As[2][128 * 32];
  __shared__ ushort_t Bs[2][128 * 32];

  const int t    = threadIdx.x;
  const int lane = t & 63;
  const int wave = t >> 6;
  const int wm   = (wave >> 1) * 64;
  const int wn   = (wave & 1) * 64;
  const long z   = blockIdx.z;

  const ushort_t* Ab = Z + z * 2048 * 1024 + (long)blockIdx.y * 128 * K;
  const ushort_t* Bb = Xh + z * 2048 * 1024 + (long)blockIdx.x * 128 * K;
  __half* Sb = S + z * 2048 * 2048;

  const int ldr = t >> 2;
  const int swzs = (ldr & 3) ^ ((ldr >> 2) & 3);
  const int ldc = ((t & 3) ^ swzs) * 8;
  const int frow = lane & 15;
  const int fsz  = (frow & 3) ^ ((frow >> 2) & 3);
  const int fo   = (((lane >> 4) ^ fsz)) * 8;

  f32x4 acc[4][4];
  const f32x4 zero = {0.0f, 0.0f, 0.0f, 0.0f};
#pragma unroll
  for (int i = 0; i < 4; ++i)
#pragma unroll
    for (int j = 0; j < 4; ++j) acc[i][j] = zero;

  for (int k0 = 0; k0 < K; k0 += 64) {
    __syncthreads();
    const ushort_t* ga = Ab + (long)ldr * K + k0 + ldc;
    const ushort_t* gb = Bb + (long)ldr * K + k0 + ldc;
#pragma unroll
    for (int h = 0; h < 2; ++h) {
      async_load16(ga + h * 32,                &As[h][t * 8]);
      async_load16(ga + h * 32 + 64 * (long)K, &As[h][2048 + t * 8]);
      async_load16(gb + h * 32,                &Bs[h][t * 8]);
      async_load16(gb + h * 32 + 64 * (long)K, &Bs[h][2048 + t * 8]);
    }
    __syncthreads();
#pragma unroll
    for (int h = 0; h < 2; ++h) {
      f16x8 af[4], bf[4];
#pragma unroll
      for (int i = 0; i < 4; ++i) {
        af[i] = *(const f16x8*)&As[h][(wm + i * 16 + frow) * 32 + fo];
        bf[i] = *(const f16x8*)&Bs[h][(wn + i * 16 + frow) * 32 + fo];
      }
#pragma unroll
      for (int mi = 0; mi < 4; ++mi)
#pragma unroll
        for (int ni = 0; ni < 4; ++ni)
          acc[mi][ni] = __builtin_amdgcn_mfma_f32_16x16x32_f16(af[mi], bf[ni], acc[mi][ni], 0, 0, 0);
    }
  }

  const int er = (lane >> 4) * 4;
  const int ec = lane & 15;

  // per-64-col-chunk row max/expsum; this wave owns chunk cc.
  const int cc = blockIdx.x * 2 + (wave & 1);   // 0..31
  float* PMb = PM + z * 32 * 2048 + (long)cc * 2048;
  float* PSb = PS + z * 32 * 2048 + (long)cc * 2048;

#pragma unroll
  for (int mi = 0; mi < 4; ++mi)
#pragma unroll
    for (int r = 0; r < 4; ++r) {
      float m = fmaxf(fmaxf(acc[mi][0][r], acc[mi][1][r]),
                      fmaxf(acc[mi][2][r], acc[mi][3][r]));
      m = fmaxf(m, __shfl_xor(m, 1));
      m = fmaxf(m, __shfl_xor(m, 2));
      m = fmaxf(m, __shfl_xor(m, 4));
      m = fmaxf(m, __shfl_xor(m, 8));
      float s = 0.0f;
#pragma unroll
      for (int ni = 0; ni < 4; ++ni) {
        const float e = __expf(acc[mi][ni][r] - m);
        acc[mi][ni][r] = e;
        s += e;
      }
      s += __shfl_xor(s, 1);
      s += __shfl_xor(s, 2);
      s += __shfl_xor(s, 4);
      s += __shfl_xor(s, 8);
      if (ec == 0) {
        const long row = (long)blockIdx.y * 128 + wm + mi * 16 + er + r;
        PMb[row] = m;
        PSb[row] = s;
      }
    }

#pragma unroll
  for (int ni = 0; ni < 4; ++ni) {
    const long col = (long)blockIdx.x * 128 + wn + ni * 16 + ec;
#pragma unroll
    for (int mi = 0; mi < 4; ++mi)
#pragma unroll
      for (int r = 0; r < 4; ++r) {
        const long grow = (long)blockIdx.y * 128 + wm + mi * 16 + er + r;
        Sb[grow * 2048 + col] = __float2half(acc[mi][ni][r]);
      }
  }
}

// ---------------------------------------------------------------------------
// Fold 32 chunk partials into per-(row,chunk) scale = exp(pm-m)/l.
// ---------------------------------------------------------------------------
__global__ __launch_bounds__(256)
void softmax_reduce_kernel(const float* __restrict__ PM, const float* __restrict__ PS,
                           float* __restrict__ Sc)
{
  const int r = blockIdx.x * 256 + threadIdx.x;
  const int b = r >> 11, row = r & 2047;
  const long base = (long)b * 32 * 2048 + row;
  float m = -3.4e38f;
#pragma unroll
  for (int cb = 0; cb < 32; ++cb) m = fmaxf(m, PM[base + cb * 2048]);
  float l = 0.0f;
#pragma unroll
  for (int cb = 0; cb < 32; ++cb) l += PS[base + cb * 2048] * __expf(PM[base + cb * 2048] - m);
  const float inv = 1.0f / l;
#pragma unroll
  for (int cb = 0; cb < 32; ++cb) Sc[base + cb * 2048] = __expf(PM[base + cb * 2048] - m) * inv;
}

// ---------------------------------------------------------------------------
// PV: Out[m][e] = sum_k (S[m][k]*scale[m][k>>6]) * Vt[e][k]. Grid (8,16,B).
// ---------------------------------------------------------------------------
__global__ __launch_bounds__(256)
void pv_gemm_kernel(const ushort_t* __restrict__ S, const ushort_t* __restrict__ Vt,
                    const float* __restrict__ Sc, float* __restrict__ Out)
{
  const int K = 2048;
  __shared__ ushort_t As[2][128 * 32];
  __shared__ ushort_t Bs[2][128 * 32];

  const int t    = threadIdx.x;
  const int lane = t & 63;
  const int wave = t >> 6;
  const int wm   = (wave >> 1) * 64;
  const int wn   = (wave & 1) * 64;
  const long z   = blockIdx.z;

  const ushort_t* Ab = S + z * 2048 * 2048 + (long)blockIdx.y * 128 * K;
  const ushort_t* Bb = Vt + z * 1024 * 2048 + (long)blockIdx.x * 128 * K;
  const float* Scb = Sc + z * 32 * 2048;
  float* Cb = Out + z * 2048 * 1024;

  const int ldr = t >> 2;
  const int swzs = (ldr & 3) ^ ((ldr >> 2) & 3);
  const int ldc = ((t & 3) ^ swzs) * 8;
  const int frow = lane & 15;
  const int fsz  = (frow & 3) ^ ((frow >> 2) & 3);
  const int fo   = (((lane >> 4) ^ fsz)) * 8;

  const int arow0 = blockIdx.y * 128 + wm + frow;

  f32x4 acc[4][4];
  const f32x4 zero = {0.0f, 0.0f, 0.0f, 0.0f};
#pragma unroll
  for (int i = 0; i < 4; ++i)
#pragma unroll
    for (int j = 0; j < 4; ++j) acc[i][j] = zero;

  for (int k0 = 0; k0 < K; k0 += 64) {
    const int cb = k0 >> 6;
    _Float16 sc16[4];
#pragma unroll
    for (int i = 0; i < 4; ++i)
      sc16[i] = (_Float16)Scb[(long)cb * 2048 + arow0 + i * 16];

    __syncthreads();
    const ushort_t* ga = Ab + (long)ldr * K + k0 + ldc;
    const ushort_t* gb = Bb + (long)ldr * K + k0 + ldc;
#pragma unroll
    for (int h = 0; h < 2; ++h) {
      async_load16(ga + h * 32,                &As[h][t * 8]);
      async_load16(ga + h * 32 + 64 * (long)K, &As[h][2048 + t * 8]);
      async_load16(gb + h * 32,                &Bs[h][t * 8]);
      async_load16(gb + h * 32 + 64 * (long)K, &Bs[h][2048 + t * 8]);
    }
    __syncthreads();
#pragma unroll
    for (int h = 0; h < 2; ++h) {
      f16x8 af[4], bf[4];
#pragma unroll
      for (int i = 0; i < 4; ++i) {
        af[i] = *(const f16x8*)&As[h][(wm + i * 16 + frow) * 32 + fo] * sc16[i];
        bf[i] = *(const f16x8*)&Bs[h][(wn + i * 16 + frow) * 32 + fo];
      }
#pragma unroll
      for (int mi = 0; mi < 4; ++mi)
#pragma unroll
        for (int ni = 0; ni < 4; ++ni)
          acc[mi][ni] = __builtin_amdgcn_mfma_f32_16x16x32_f16(af[mi], bf[ni], acc[mi][ni], 0, 0, 0);
    }
  }

  const int er = (lane >> 4) * 4;
  const int ec = lane & 15;
#pragma unroll
  for (int ni = 0; ni < 4; ++ni) {
    const int gcol = blockIdx.x * 128 + wn + ni * 16 + ec;
#pragma unroll
    for (int mi = 0; mi < 4; ++mi) {
#pragma unroll
      for (int r = 0; r < 4; ++r) {
        const long grow = (long)blockIdx.y * 128 + wm + mi * 16 + er + r;
        Cb[grow * 1024 + gcol] = acc[mi][ni][r];
      }
    }
  }
}

// ---------------------------------------------------------------------------
// Combined prep: straight cvt X->Xh (nx blocks), Wq->Wqh (512), Wk->Wkh (512),
// then Wv transpose-cvt -> Wvt (1024 tile blocks). Grid = nx + 2048.
// ---------------------------------------------------------------------------
__global__ __launch_bounds__(256)
void prep_kernel(const float* __restrict__ X, __half* __restrict__ Xh, int nx,
                 const float* __restrict__ Wq, __half* __restrict__ Wqh,
                 const float* __restrict__ Wk, __half* __restrict__ Wkh,
                 const float* __restrict__ Wv, __half* __restrict__ Wvt)
{
  const int bid = blockIdx.x;
  const int tid = threadIdx.x;
  if (bid < nx + 1024) {
    const float* src; __half* dst; long base;
    if (bid < nx)          { src = X;  dst = Xh;  base = (long)bid * 2048; }
    else if (bid < nx+512) { src = Wq; dst = Wqh; base = (long)(bid - nx) * 2048; }
    else                   { src = Wk; dst = Wkh; base = (long)(bid - nx - 512) * 2048; }
    const long i = base + (long)tid * 8;
    const float4 a = *(const float4*)(src + i);
    const float4 b = *(const float4*)(src + i + 4);
    f16x8 h;
    h[0] = (_Float16)a.x; h[1] = (_Float16)a.y; h[2] = (_Float16)a.z; h[3] = (_Float16)a.w;
    h[4] = (_Float16)b.x; h[5] = (_Float16)b.y; h[6] = (_Float16)b.z; h[7] = (_Float16)b.w;
    *(f16x8*)((ushort_t*)dst + i) = h;
  } else {
    __shared__ float tile[32][33];
    const int t2 = bid - (nx + 1024);
    const int c0 = (t2 & 31) * 32;
    const int r0 = (t2 >> 5) * 32;
    const int tx = tid & 31;
    const int ty = tid >> 5;
#pragma unroll
    for (int i = 0; i < 32; i += 8)
      tile[ty + i][tx] = Wv[(long)(r0 + ty + i) * 1024 + (c0 + tx)];
    __syncthreads();
#pragma unroll
    for (int i = 0; i < 32; i += 8)
      Wvt[(long)(c0 + ty + i) * 1024 + (r0 + tx)] = __float2half(tile[tx][ty + i]);
  }
}

// ---------------------------------------------------------------------------
// fp32 -> fp16 elementwise (fallback path only).
// ---------------------------------------------------------------------------
__global__ __launch_bounds__(256)
void cvt_f32_f16_kernel(const float* __restrict__ src, __half* __restrict__ dst, long n)
{
  const long i = ((long)blockIdx.x * 256 + threadIdx.x) * 8;
  if (i + 8 > n) return;
  const float4 a = *(const float4*)(src + i);
  const float4 b = *(const float4*)(src + i + 4);
  f16x8 h;
  h[0] = (_Float16)a.x; h[1] = (_Float16)a.y; h[2] = (_Float16)a.z; h[3] = (_Float16)a.w;
  h[4] = (_Float16)b.x; h[5] = (_Float16)b.y; h[6] = (_Float16)b.z; h[7] = (_Float16)b.w;
  *(f16x8*)((ushort_t*)dst + i) = h;
}

// ---------------------------------------------------------------------------
// wkbq[d] = sum_e Wk[d][e] * bq[e] (fp32). One wave per row: grid 256 x 256.
// Coalesced float4 per lane, wave shuffle-reduce.
// ---------------------------------------------------------------------------
__global__ __launch_bounds__(256)
void wkbq_kernel(const float* __restrict__ Wk, const float* __restrict__ bq,
                 float* __restrict__ wkbq)
{
  const int wave = threadIdx.x >> 6, lane = threadIdx.x & 63;
  const int d = blockIdx.x * 4 + wave;
  const float* row = Wk + (long)d * 1024;
  float acc = 0.0f;
#pragma unroll
  for (int p = 0; p < 4; ++p) {
    const int e = p * 256 + lane * 4;
    const float4 wv = *(const float4*)(row + e);
    const float4 bv = *(const float4*)(bq + e);
    acc += wv.x * bv.x + wv.y * bv.y + wv.z * bv.z + wv.w * bv.w;
  }
#pragma unroll
  for (int off = 32; off > 0; off >>= 1) acc += __shfl_xor(acc, off, 64);
  if (lane == 0) wkbq[d] = acc;
}

// ---------------------------------------------------------------------------
extern "C" void kernel_launch(void* const* d_in, const int* in_sizes, int n_in,
                              void* d_out, int out_size, void* d_ws, size_t ws_size,
                              hipStream_t stream)
{
  const int  Bb = 4, Nn = 2048, Dd = 1024;
  const long BN = (long)Bb * Nn;  // 8192

  const float* X  = (const float*)d_in[0];
  const float* Wq = (const float*)d_in[1];
  const float* bq = (const float*)d_in[2];
  const float* Wk = (const float*)d_in[3];
  const float* bk = (const float*)d_in[4];  (void)bk;  // cancels in softmax
  const float* Wv = (const float*)d_in[5];
  const float* bv = (const float*)d_in[6];
  float* Out      = (float*)d_out;

  uint8_t* w = (uint8_t*)d_ws;
  ushort_t* Wqh   = (ushort_t*)w;  w += (size_t)Dd * Dd * 2;
  ushort_t* Wkh   = (ushort_t*)w;  w += (size_t)Dd * Dd * 2;
  ushort_t* MtWvt = (ushort_t*)w;  w += (size_t)2 * Dd * Dd * 2;  // [Mt | Wvt]
  ushort_t* Mt  = MtWvt;
  ushort_t* Wvt = MtWvt + (size_t)Dd * Dd;
  float* wkbq = (float*)w;  w += (size_t)Dd * 4;

  const size_t statsBytes = (size_t)Bb * 32 * Nn * 4;
  const size_t fullNeed = (size_t)8 * Dd * Dd * 2 + Dd * 4
                        + 3 * ((size_t)BN * Dd * 2)      // Xh, Zh, Vt
                        + (size_t)Bb * Nn * Nn * 2       // S fp16
                        + 3 * statsBytes;

  // wkbq depends only on raw fp32 inputs; 256-block grid, ~2 us
  wkbq_kernel<<<dim3(Dd / 4), 256, 0, stream>>>(Wk, bq, wkbq);

  if (ws_size >= fullNeed) {
    ushort_t* Xh = (ushort_t*)w;  w += (size_t)BN * Dd * 2;
    ushort_t* Zh = (ushort_t*)w;  w += (size_t)BN * Dd * 2;
    ushort_t* Vt = (ushort_t*)w;  w += (size_t)BN * Dd * 2;  // [B][Dd][Nn]
    ushort_t* S  = (ushort_t*)w;  w += (size_t)Bb * Nn * Nn * 2;
    float*    PM = (float*)w;     w += statsBytes;
    float*    PS = (float*)w;     w += statsBytes;
    float*    Sc = (float*)w;

    const int nx = (int)(BN * Dd / 2048);  // 4096
    prep_kernel<<<dim3(nx + 2048), 256, 0, stream>>>(
        X, (__half*)Xh, nx, Wq, (__half*)Wqh, Wk, (__half*)Wkh, Wv, (__half*)Wvt);

    // Mt[d'][d] = sum_e Wk[d'][e] Wq[d][e]  (= M^T, the BT operand for Z)
    gemm_f16_kernel<<<dim3(Dd / 128, Dd / 128), 256, 0, stream>>>(Wkh, Wqh, (__half*)Mt);

    // Z' = X M^T + wkbq ; V = X Wv + bv (transposed store)
    zv_gemm_kernel<<<dim3(2 * Dd / 128, BN / 128), 256, 0, stream>>>(
        Xh, MtWvt, wkbq, bv, (__half*)Zh, Vt);

    // S = Z' X^T, fused partial softmax
    qk_gemm_kernel<<<dim3(Nn / 128, Nn / 128, Bb), 256, 0, stream>>>(
        Zh, Xh, (__half*)S, PM, PS);

    softmax_reduce_kernel<<<dim3((unsigned)(Bb * Nn / 256)), 256, 0, stream>>>(PM, PS, Sc);

    pv_gemm_kernel<<<dim3(Dd / 128, Nn / 128, Bb), 256, 0, stream>>>(S, Vt, Sc, Out);
  } else {
    // Per-batch fallback (~30 MB ws)
    ushort_t* Xh = (ushort_t*)w;  w += (size_t)Nn * Dd * 2;
    ushort_t* Zh = (ushort_t*)w;  w += (size_t)Nn * Dd * 2;
    ushort_t* Vt = (ushort_t*)w;  w += (size_t)Nn * Dd * 2;
    ushort_t* S  = (ushort_t*)w;  w += (size_t)Nn * Nn * 2;
    float*    PM = (float*)w;     w += (size_t)32 * Nn * 4;
    float*    PS = (float*)w;     w += (size_t)32 * Nn * 4;
    float*    Sc = (float*)w;

    prep_kernel<<<dim3(2048), 256, 0, stream>>>(
        nullptr, nullptr, 0, Wq, (__half*)Wqh, Wk, (__half*)Wkh, Wv, (__half*)Wvt);
    gemm_f16_kernel<<<dim3(Dd / 128, Dd / 128), 256, 0, stream>>>(Wkh, Wqh, (__half*)Mt);

    for (int b = 0; b < Bb; ++b) {
      const float* Xb = X + (long)b * Nn * Dd;
      cvt_f32_f16_kernel<<<dim3((unsigned)((long)Nn * Dd / (8 * 256))), 256, 0, stream>>>(
          Xb, (__half*)Xh, (long)Nn * Dd);
      zv_gemm_kernel<<<dim3(2 * Dd / 128, Nn / 128), 256, 0, stream>>>(
          Xh, MtWvt, wkbq, bv, (__half*)Zh, Vt);
      qk_gemm_kernel<<<dim3(Nn / 128, Nn / 128, 1), 256, 0, stream>>>(
          Zh, Xh, (__half*)S, PM, PS);
      softmax_reduce_kernel<<<dim3(Nn / 256), 256, 0, stream>>>(PM, PS, Sc);
      pv_gemm_kernel<<<dim3(Dd / 128, Nn / 128, 1), 256, 0, stream>>>(
          S, Vt, Sc, Out + (long)b * Nn * Dd);
    }
  }
}

// Round 9
// 283.860 us; speedup vs baseline: 1.1489x; 1.0068x over previous
//
#include <hip/hip_runtime.h>
#include <hip/hip_bf16.h>
#include <hip/hip_fp16.h>
#include <stdint.h>
#include <math.h>

// ---------------------------------------------------------------------------
// AttentionLayer: Q=XWq+bq, K=XWk+bk, V=XWv+bv; O = softmax(QK^T) V
// B=4, N=2048, D=1024. fp32 I/O; internals fp16, accumulation fp32.
// R9: same algebra as R8 (S = X·M·X^T + col-bias; M=Wq·Wk^T; rowconst
// cancels in softmax) but the 4 serial prologue jobs (X cvt, Wv transpose,
// wkbq GEMV, Mt GEMM) are merged into ONE kernel. Mt is computed directly
// from fp32 inputs (float4 load -> in-reg cvt -> ds_write_b128, same swizzled
// LDS layout) so the serial 64-block gemm_f16 round and the Wq/Wk fp16
// conversions are deleted. Chain: prep -> zv -> qk -> reduce -> pv.
// ---------------------------------------------------------------------------

typedef unsigned short ushort_t;
typedef __attribute__((ext_vector_type(8))) _Float16  f16x8;
typedef __attribute__((ext_vector_type(4))) _Float16  f16x4;
typedef __attribute__((ext_vector_type(4))) float     f32x4;

__device__ __forceinline__ void async_load16(const void* g, void* l) {
  __builtin_amdgcn_global_load_lds(
      (const __attribute__((address_space(1))) void*)g,
      (__attribute__((address_space(3))) void*)l, 16, 0, 0);
}

// ---------------------------------------------------------------------------
// ZV GEMM: A = Xh [M][1024], BT = [Mt | Wvt] [2048][1024].
// blockIdx.x<8: Z' = X·M^T + wkbq (fp16); >=8: V = X·Wv+bv stored transposed
// Vt[b][e][m]. Swizzled LDS, 2 BK=32 steps per barrier pair.
// ---------------------------------------------------------------------------
__global__ __launch_bounds__(256)
void zv_gemm_kernel(const ushort_t* __restrict__ A, const ushort_t* __restrict__ BT,
                    const float* __restrict__ wkbq, const float* __restrict__ bvp,
                    __half* __restrict__ Zh, ushort_t* __restrict__ Vt)
{
  const int K = 1024;
  __shared__ ushort_t As[2][128 * 32];
  __shared__ ushort_t Bs[2][128 * 32];

  const int t    = threadIdx.x;
  const int lane = t & 63;
  const int wave = t >> 6;
  const int wm   = (wave >> 1) * 64;
  const int wn   = (wave & 1) * 64;

  const ushort_t* Ab = A + (long)blockIdx.y * 128 * K;
  const ushort_t* Bb = BT + (long)blockIdx.x * 128 * K;

  const int ldr = t >> 2;
  const int swzs = (ldr & 3) ^ ((ldr >> 2) & 3);
  const int ldc = ((t & 3) ^ swzs) * 8;
  const int frow = lane & 15;
  const int fsz  = (frow & 3) ^ ((frow >> 2) & 3);
  const int fo   = (((lane >> 4) ^ fsz)) * 8;

  f32x4 acc[4][4];
  const f32x4 zero = {0.0f, 0.0f, 0.0f, 0.0f};
#pragma unroll
  for (int i = 0; i < 4; ++i)
#pragma unroll
    for (int j = 0; j < 4; ++j) acc[i][j] = zero;

  for (int k0 = 0; k0 < K; k0 += 64) {
    __syncthreads();
    const ushort_t* ga = Ab + (long)ldr * K + k0 + ldc;
    const ushort_t* gb = Bb + (long)ldr * K + k0 + ldc;
#pragma unroll
    for (int h = 0; h < 2; ++h) {
      async_load16(ga + h * 32,                &As[h][t * 8]);
      async_load16(ga + h * 32 + 64 * (long)K, &As[h][2048 + t * 8]);
      async_load16(gb + h * 32,                &Bs[h][t * 8]);
      async_load16(gb + h * 32 + 64 * (long)K, &Bs[h][2048 + t * 8]);
    }
    __syncthreads();
#pragma unroll
    for (int h = 0; h < 2; ++h) {
      f16x8 af[4], bf[4];
#pragma unroll
      for (int i = 0; i < 4; ++i) {
        af[i] = *(const f16x8*)&As[h][(wm + i * 16 + frow) * 32 + fo];
        bf[i] = *(const f16x8*)&Bs[h][(wn + i * 16 + frow) * 32 + fo];
      }
#pragma unroll
      for (int mi = 0; mi < 4; ++mi)
#pragma unroll
        for (int ni = 0; ni < 4; ++ni)
          acc[mi][ni] = __builtin_amdgcn_mfma_f32_16x16x32_f16(af[mi], bf[ni], acc[mi][ni], 0, 0, 0);
    }
  }

  const int er = (lane >> 4) * 4;
  const int ec = lane & 15;
  const int tgt = blockIdx.x >> 3;  // 0: Z, 1: V (block-uniform)
#pragma unroll
  for (int ni = 0; ni < 4; ++ni) {
    const int c = (blockIdx.x & 7) * 128 + wn + ni * 16 + ec;  // 0..1023
    const float bval = (tgt == 0) ? wkbq[c] : bvp[c];
#pragma unroll
    for (int mi = 0; mi < 4; ++mi) {
      const long grow0 = (long)blockIdx.y * 128 + wm + mi * 16 + er;
      if (tgt == 0) {
#pragma unroll
        for (int r = 0; r < 4; ++r)
          Zh[(grow0 + r) * 1024 + c] = __float2half(acc[mi][ni][r] + bval);
      } else {
        const long b  = grow0 >> 11;       // batch (2048 rows per batch)
        const long ml = grow0 & 2047;
        f16x4 v4;
#pragma unroll
        for (int r = 0; r < 4; ++r) v4[r] = (_Float16)(acc[mi][ni][r] + bval);
        *(f16x4*)&Vt[b * 2097152 + (long)c * 2048 + ml] = v4;
      }
    }
  }
}

// ---------------------------------------------------------------------------
// S = Z'·X^T with fused partial softmax, 64-col chunk stats.
// S[row][col] = exp(s - m_chunk) fp16; PM/PS[z][32][2048]. Grid (16,16,B).
// ---------------------------------------------------------------------------
__global__ __launch_bounds__(256)
void qk_gemm_kernel(const ushort_t* __restrict__ Z, const ushort_t* __restrict__ Xh,
                    __half* __restrict__ S, float* __restrict__ PM, float* __restrict__ PS)
{
  const int K = 1024;
  __shared__ ushort_t As[2][128 * 32];
  __shared__ ushort_t Bs[2][128 * 32];

  const int t    = threadIdx.x;
  const int lane = t & 63;
  const int wave = t >> 6;
  const int wm   = (wave >> 1) * 64;
  const int wn   = (wave & 1) * 64;
  const long z   = blockIdx.z;

  const ushort_t* Ab = Z + z * 2048 * 1024 + (long)blockIdx.y * 128 * K;
  const ushort_t* Bb = Xh + z * 2048 * 1024 + (long)blockIdx.x * 128 * K;
  __half* Sb = S + z * 2048 * 2048;

  const int ldr = t >> 2;
  const int swzs = (ldr & 3) ^ ((ldr >> 2) & 3);
  const int ldc = ((t & 3) ^ swzs) * 8;
  const int frow = lane & 15;
  const int fsz  = (frow & 3) ^ ((frow >> 2) & 3);
  const int fo   = (((lane >> 4) ^ fsz)) * 8;

  f32x4 acc[4][4];
  const f32x4 zero = {0.0f, 0.0f, 0.0f, 0.0f};
#pragma unroll
  for (int i = 0; i < 4; ++i)
#pragma unroll
    for (int j = 0; j < 4; ++j) acc[i][j] = zero;

  for (int k0 = 0; k0 < K; k0 += 64) {
    __syncthreads();
    const ushort_t* ga = Ab + (long)ldr * K + k0 + ldc;
    const ushort_t* gb = Bb + (long)ldr * K + k0 + ldc;
#pragma unroll
    for (int h = 0; h < 2; ++h) {
      async_load16(ga + h * 32,                &As[h][t * 8]);
      async_load16(ga + h * 32 + 64 * (long)K, &As[h][2048 + t * 8]);
      async_load16(gb + h * 32,                &Bs[h][t * 8]);
      async_load16(gb + h * 32 + 64 * (long)K, &Bs[h][2048 + t * 8]);
    }
    __syncthreads();
#pragma unroll
    for (int h = 0; h < 2; ++h) {
      f16x8 af[4], bf[4];
#pragma unroll
      for (int i = 0; i < 4; ++i) {
        af[i] = *(const f16x8*)&As[h][(wm + i * 16 + frow) * 32 + fo];
        bf[i] = *(const f16x8*)&Bs[h][(wn + i * 16 + frow) * 32 + fo];
      }
#pragma unroll
      for (int mi = 0; mi < 4; ++mi)
#pragma unroll
        for (int ni = 0; ni < 4; ++ni)
          acc[mi][ni] = __builtin_amdgcn_mfma_f32_16x16x32_f16(af[mi], bf[ni], acc[mi][ni], 0, 0, 0);
    }
  }

  const int er = (lane >> 4) * 4;
  const int ec = lane & 15;

  // per-64-col-chunk row max/expsum; this wave owns chunk cc.
  const int cc = blockIdx.x * 2 + (wave & 1);   // 0..31
  float* PMb = PM + z * 32 * 2048 + (long)cc * 2048;
  float* PSb = PS + z * 32 * 2048 + (long)cc * 2048;

#pragma unroll
  for (int mi = 0; mi < 4; ++mi)
#pragma unroll
    for (int r = 0; r < 4; ++r) {
      float m = fmaxf(fmaxf(acc[mi][0][r], acc[mi][1][r]),
                      fmaxf(acc[mi][2][r], acc[mi][3][r]));
      m = fmaxf(m, __shfl_xor(m, 1));
      m = fmaxf(m, __shfl_xor(m, 2));
      m = fmaxf(m, __shfl_xor(m, 4));
      m = fmaxf(m, __shfl_xor(m, 8));
      float s = 0.0f;
#pragma unroll
      for (int ni = 0; ni < 4; ++ni) {
        const float e = __expf(acc[mi][ni][r] - m);
        acc[mi][ni][r] = e;
        s += e;
      }
      s += __shfl_xor(s, 1);
      s += __shfl_xor(s, 2);
      s += __shfl_xor(s, 4);
      s += __shfl_xor(s, 8);
      if (ec == 0) {
        const long row = (long)blockIdx.y * 128 + wm + mi * 16 + er + r;
        PMb[row] = m;
        PSb[row] = s;
      }
    }

#pragma unroll
  for (int ni = 0; ni < 4; ++ni) {
    const long col = (long)blockIdx.x * 128 + wn + ni * 16 + ec;
#pragma unroll
    for (int mi = 0; mi < 4; ++mi)
#pragma unroll
      for (int r = 0; r < 4; ++r) {
        const long grow = (long)blockIdx.y * 128 + wm + mi * 16 + er + r;
        Sb[grow * 2048 + col] = __float2half(acc[mi][ni][r]);
      }
  }
}

// ---------------------------------------------------------------------------
// Fold 32 chunk partials into per-(row,chunk) scale = exp(pm-m)/l.
// ---------------------------------------------------------------------------
__global__ __launch_bounds__(256)
void softmax_reduce_kernel(const float* __restrict__ PM, const float* __restrict__ PS,
                           float* __restrict__ Sc)
{
  const int r = blockIdx.x * 256 + threadIdx.x;
  const int b = r >> 11, row = r & 2047;
  const long base = (long)b * 32 * 2048 + row;
  float m = -3.4e38f;
#pragma unroll
  for (int cb = 0; cb < 32; ++cb) m = fmaxf(m, PM[base + cb * 2048]);
  float l = 0.0f;
#pragma unroll
  for (int cb = 0; cb < 32; ++cb) l += PS[base + cb * 2048] * __expf(PM[base + cb * 2048] - m);
  const float inv = 1.0f / l;
#pragma unroll
  for (int cb = 0; cb < 32; ++cb) Sc[base + cb * 2048] = __expf(PM[base + cb * 2048] - m) * inv;
}

// ---------------------------------------------------------------------------
// PV: Out[m][e] = sum_k (S[m][k]*scale[m][k>>6]) * Vt[e][k]. Grid (8,16,B).
// ---------------------------------------------------------------------------
__global__ __launch_bounds__(256)
void pv_gemm_kernel(const ushort_t* __restrict__ S, const ushort_t* __restrict__ Vt,
                    const float* __restrict__ Sc, float* __restrict__ Out)
{
  const int K = 2048;
  __shared__ ushort_t As[2][128 * 32];
  __shared__ ushort_t Bs[2][128 * 32];

  const int t    = threadIdx.x;
  const int lane = t & 63;
  const int wave = t >> 6;
  const int wm   = (wave >> 1) * 64;
  const int wn   = (wave & 1) * 64;
  const long z   = blockIdx.z;

  const ushort_t* Ab = S + z * 2048 * 2048 + (long)blockIdx.y * 128 * K;
  const ushort_t* Bb = Vt + z * 1024 * 2048 + (long)blockIdx.x * 128 * K;
  const float* Scb = Sc + z * 32 * 2048;
  float* Cb = Out + z * 2048 * 1024;

  const int ldr = t >> 2;
  const int swzs = (ldr & 3) ^ ((ldr >> 2) & 3);
  const int ldc = ((t & 3) ^ swzs) * 8;
  const int frow = lane & 15;
  const int fsz  = (frow & 3) ^ ((frow >> 2) & 3);
  const int fo   = (((lane >> 4) ^ fsz)) * 8;

  const int arow0 = blockIdx.y * 128 + wm + frow;

  f32x4 acc[4][4];
  const f32x4 zero = {0.0f, 0.0f, 0.0f, 0.0f};
#pragma unroll
  for (int i = 0; i < 4; ++i)
#pragma unroll
    for (int j = 0; j < 4; ++j) acc[i][j] = zero;

  for (int k0 = 0; k0 < K; k0 += 64) {
    const int cb = k0 >> 6;
    _Float16 sc16[4];
#pragma unroll
    for (int i = 0; i < 4; ++i)
      sc16[i] = (_Float16)Scb[(long)cb * 2048 + arow0 + i * 16];

    __syncthreads();
    const ushort_t* ga = Ab + (long)ldr * K + k0 + ldc;
    const ushort_t* gb = Bb + (long)ldr * K + k0 + ldc;
#pragma unroll
    for (int h = 0; h < 2; ++h) {
      async_load16(ga + h * 32,                &As[h][t * 8]);
      async_load16(ga + h * 32 + 64 * (long)K, &As[h][2048 + t * 8]);
      async_load16(gb + h * 32,                &Bs[h][t * 8]);
      async_load16(gb + h * 32 + 64 * (long)K, &Bs[h][2048 + t * 8]);
    }
    __syncthreads();
#pragma unroll
    for (int h = 0; h < 2; ++h) {
      f16x8 af[4], bf[4];
#pragma unroll
      for (int i = 0; i < 4; ++i) {
        af[i] = *(const f16x8*)&As[h][(wm + i * 16 + frow) * 32 + fo] * sc16[i];
        bf[i] = *(const f16x8*)&Bs[h][(wn + i * 16 + frow) * 32 + fo];
      }
#pragma unroll
      for (int mi = 0; mi < 4; ++mi)
#pragma unroll
        for (int ni = 0; ni < 4; ++ni)
          acc[mi][ni] = __builtin_amdgcn_mfma_f32_16x16x32_f16(af[mi], bf[ni], acc[mi][ni], 0, 0, 0);
    }
  }

  const int er = (lane >> 4) * 4;
  const int ec = lane & 15;
#pragma unroll
  for (int ni = 0; ni < 4; ++ni) {
    const int gcol = blockIdx.x * 128 + wn + ni * 16 + ec;
#pragma unroll
    for (int mi = 0; mi < 4; ++mi) {
#pragma unroll
      for (int r = 0; r < 4; ++r) {
        const long grow = (long)blockIdx.y * 128 + wm + mi * 16 + er + r;
        Cb[grow * 1024 + gcol] = acc[mi][ni][r];
      }
    }
  }
}

// ---------------------------------------------------------------------------
// Merged prep. Grid layout (block-uniform branches; longest jobs first):
//   [0,64):          Mt = Wk·Wq^T from fp32 (manual stage + in-reg cvt)
//   [64,320):        wkbq[d] = Wk[d]·bq (wave per row, 4 rows/block)
//   [320,1344):      Wv transpose-cvt -> Wvt[e][k] fp16
//   [1344,1344+nx):  X -> Xh fp16 (2048 elems/block)
// ---------------------------------------------------------------------------
__global__ __launch_bounds__(256)
void prep_kernel(const float* __restrict__ X, __half* __restrict__ Xh, int nx,
                 const float* __restrict__ Wq, const float* __restrict__ Wk,
                 const float* __restrict__ Wv, __half* __restrict__ Wvt,
                 const float* __restrict__ bq, float* __restrict__ wkbq,
                 __half* __restrict__ Mt)
{
  __shared__ ushort_t As[2][128 * 32];
  __shared__ ushort_t Bs[2][128 * 32];
  __shared__ float tile[32][33];

  const int bid = blockIdx.x;
  const int tid = threadIdx.x;

  if (bid < 64) {
    // --- Mt GEMM block: C[128x128] = Wk-tile · Wq-tile^T, fp32 sources ---
    const int bx = bid & 7, by = bid >> 3;
    const int lane = tid & 63, wave = tid >> 6;
    const int wm = (wave >> 1) * 64, wn = (wave & 1) * 64;
    const int ldr = tid >> 2;
    const int swzs = (ldr & 3) ^ ((ldr >> 2) & 3);
    const int ldc = ((tid & 3) ^ swzs) * 8;   // global col chunk (elems)
    const int frow = lane & 15;
    const int fsz  = (frow & 3) ^ ((frow >> 2) & 3);
    const int fo   = (((lane >> 4) ^ fsz)) * 8;

    const float* Ar = Wk + (long)(by * 128 + ldr) * 1024;
    const float* Br = Wq + (long)(bx * 128 + ldr) * 1024;

    f32x4 acc[4][4];
    const f32x4 zero = {0.0f, 0.0f, 0.0f, 0.0f};
#pragma unroll
    for (int i = 0; i < 4; ++i)
#pragma unroll
      for (int j = 0; j < 4; ++j) acc[i][j] = zero;

    for (int k0 = 0; k0 < 1024; k0 += 64) {
      __syncthreads();
#pragma unroll
      for (int h = 0; h < 2; ++h) {
        const int kc = k0 + h * 32 + ldc;
#pragma unroll
        for (int half = 0; half < 2; ++half) {   // rows ldr, ldr+64
          const long roff = (long)half * 64 * 1024;
          const float4 a0 = *(const float4*)(Ar + roff + kc);
          const float4 a1 = *(const float4*)(Ar + roff + kc + 4);
          const float4 b0 = *(const float4*)(Br + roff + kc);
          const float4 b1 = *(const float4*)(Br + roff + kc + 4);
          f16x8 ah, bh;
          ah[0]=(_Float16)a0.x; ah[1]=(_Float16)a0.y; ah[2]=(_Float16)a0.z; ah[3]=(_Float16)a0.w;
          ah[4]=(_Float16)a1.x; ah[5]=(_Float16)a1.y; ah[6]=(_Float16)a1.z; ah[7]=(_Float16)a1.w;
          bh[0]=(_Float16)b0.x; bh[1]=(_Float16)b0.y; bh[2]=(_Float16)b0.z; bh[3]=(_Float16)b0.w;
          bh[4]=(_Float16)b1.x; bh[5]=(_Float16)b1.y; bh[6]=(_Float16)b1.z; bh[7]=(_Float16)b1.w;
          *(f16x8*)&As[h][half * 2048 + tid * 8] = ah;
          *(f16x8*)&Bs[h][half * 2048 + tid * 8] = bh;
        }
      }
      __syncthreads();
#pragma unroll
      for (int h = 0; h < 2; ++h) {
        f16x8 af[4], bf[4];
#pragma unroll
        for (int i = 0; i < 4; ++i) {
          af[i] = *(const f16x8*)&As[h][(wm + i * 16 + frow) * 32 + fo];
          bf[i] = *(const f16x8*)&Bs[h][(wn + i * 16 + frow) * 32 + fo];
        }
#pragma unroll
        for (int mi = 0; mi < 4; ++mi)
#pragma unroll
          for (int ni = 0; ni < 4; ++ni)
            acc[mi][ni] = __builtin_amdgcn_mfma_f32_16x16x32_f16(af[mi], bf[ni], acc[mi][ni], 0, 0, 0);
      }
    }

    const int er = (lane >> 4) * 4;
    const int ec = lane & 15;
#pragma unroll
    for (int ni = 0; ni < 4; ++ni) {
      const int gcol = bx * 128 + wn + ni * 16 + ec;
#pragma unroll
      for (int mi = 0; mi < 4; ++mi)
#pragma unroll
        for (int r = 0; r < 4; ++r) {
          const long grow = (long)by * 128 + wm + mi * 16 + er + r;
          Mt[grow * 1024 + gcol] = __float2half(acc[mi][ni][r]);
        }
    }
  } else if (bid < 320) {
    // --- wkbq: one wave per row, 4 rows per block ---
    const int wave = tid >> 6, lane = tid & 63;
    const int d = (bid - 64) * 4 + wave;
    const float* row = Wk + (long)d * 1024;
    float acc = 0.0f;
#pragma unroll
    for (int p = 0; p < 4; ++p) {
      const int e = p * 256 + lane * 4;
      const float4 wv = *(const float4*)(row + e);
      const float4 bv = *(const float4*)(bq + e);
      acc += wv.x * bv.x + wv.y * bv.y + wv.z * bv.z + wv.w * bv.w;
    }
#pragma unroll
    for (int off = 32; off > 0; off >>= 1) acc += __shfl_xor(acc, off, 64);
    if (lane == 0) wkbq[d] = acc;
  } else if (bid < 1344) {
    // --- Wv transpose-cvt: Wvt[c][r] = (fp16)Wv[r][c], 32x32 tile ---
    const int t2 = bid - 320;
    const int c0 = (t2 & 31) * 32;
    const int r0 = (t2 >> 5) * 32;
    const int tx = tid & 31;
    const int ty = tid >> 5;
#pragma unroll
    for (int i = 0; i < 32; i += 8)
      tile[ty + i][tx] = Wv[(long)(r0 + ty + i) * 1024 + (c0 + tx)];
    __syncthreads();
#pragma unroll
    for (int i = 0; i < 32; i += 8)
      Wvt[(long)(c0 + ty + i) * 1024 + (r0 + tx)] = __float2half(tile[tx][ty + i]);
  } else {
    // --- X cvt: 2048 elems per block ---
    const long i = (long)(bid - 1344) * 2048 + (long)tid * 8;
    const float4 a = *(const float4*)(X + i);
    const float4 b = *(const float4*)(X + i + 4);
    f16x8 h;
    h[0]=(_Float16)a.x; h[1]=(_Float16)a.y; h[2]=(_Float16)a.z; h[3]=(_Float16)a.w;
    h[4]=(_Float16)b.x; h[5]=(_Float16)b.y; h[6]=(_Float16)b.z; h[7]=(_Float16)b.w;
    *(f16x8*)((ushort_t*)Xh + i) = h;
  }
}

// ---------------------------------------------------------------------------
// fp32 -> fp16 elementwise (fallback path only).
// ---------------------------------------------------------------------------
__global__ __launch_bounds__(256)
void cvt_f32_f16_kernel(const float* __restrict__ src, __half* __restrict__ dst, long n)
{
  const long i = ((long)blockIdx.x * 256 + threadIdx.x) * 8;
  if (i + 8 > n) return;
  const float4 a = *(const float4*)(src + i);
  const float4 b = *(const float4*)(src + i + 4);
  f16x8 h;
  h[0] = (_Float16)a.x; h[1] = (_Float16)a.y; h[2] = (_Float16)a.z; h[3] = (_Float16)a.w;
  h[4] = (_Float16)b.x; h[5] = (_Float16)b.y; h[6] = (_Float16)b.z; h[7] = (_Float16)b.w;
  *(f16x8*)((ushort_t*)dst + i) = h;
}

// ---------------------------------------------------------------------------
extern "C" void kernel_launch(void* const* d_in, const int* in_sizes, int n_in,
                              void* d_out, int out_size, void* d_ws, size_t ws_size,
                              hipStream_t stream)
{
  const int  Bb = 4, Nn = 2048, Dd = 1024;
  const long BN = (long)Bb * Nn;  // 8192

  const float* X  = (const float*)d_in[0];
  const float* Wq = (const float*)d_in[1];
  const float* bq = (const float*)d_in[2];
  const float* Wk = (const float*)d_in[3];
  const float* bk = (const float*)d_in[4];  (void)bk;  // cancels in softmax
  const float* Wv = (const float*)d_in[5];
  const float* bv = (const float*)d_in[6];
  float* Out      = (float*)d_out;

  uint8_t* w = (uint8_t*)d_ws;
  ushort_t* MtWvt = (ushort_t*)w;  w += (size_t)2 * Dd * Dd * 2;  // [Mt | Wvt]
  ushort_t* Mt  = MtWvt;
  ushort_t* Wvt = MtWvt + (size_t)Dd * Dd;
  float* wkbq = (float*)w;  w += (size_t)Dd * 4;

  const size_t statsBytes = (size_t)Bb * 32 * Nn * 4;
  const size_t fullNeed = (size_t)4 * Dd * Dd * 2 + Dd * 4
                        + 3 * ((size_t)BN * Dd * 2)      // Xh, Zh, Vt
                        + (size_t)Bb * Nn * Nn * 2       // S fp16
                        + 3 * statsBytes;

  if (ws_size >= fullNeed) {
    ushort_t* Xh = (ushort_t*)w;  w += (size_t)BN * Dd * 2;
    ushort_t* Zh = (ushort_t*)w;  w += (size_t)BN * Dd * 2;
    ushort_t* Vt = (ushort_t*)w;  w += (size_t)BN * Dd * 2;  // [B][Dd][Nn]
    ushort_t* S  = (ushort_t*)w;  w += (size_t)Bb * Nn * Nn * 2;
    float*    PM = (float*)w;     w += statsBytes;
    float*    PS = (float*)w;     w += statsBytes;
    float*    Sc = (float*)w;

    const int nx = (int)(BN * Dd / 2048);  // 4096
    // prep: Mt + wkbq + Wvt + Xh in one dispatch
    prep_kernel<<<dim3(1344 + nx), 256, 0, stream>>>(
        X, (__half*)Xh, nx, Wq, Wk, Wv, (__half*)Wvt, bq, wkbq, (__half*)Mt);

    // Z' = X M^T + wkbq ; V = X Wv + bv (transposed store)
    zv_gemm_kernel<<<dim3(2 * Dd / 128, BN / 128), 256, 0, stream>>>(
        Xh, MtWvt, wkbq, bv, (__half*)Zh, Vt);

    // S = Z' X^T, fused partial softmax
    qk_gemm_kernel<<<dim3(Nn / 128, Nn / 128, Bb), 256, 0, stream>>>(
        Zh, Xh, (__half*)S, PM, PS);

    softmax_reduce_kernel<<<dim3((unsigned)(Bb * Nn / 256)), 256, 0, stream>>>(PM, PS, Sc);

    pv_gemm_kernel<<<dim3(Dd / 128, Nn / 128, Bb), 256, 0, stream>>>(S, Vt, Sc, Out);
  } else {
    // Per-batch fallback (~30 MB ws)
    ushort_t* Xh = (ushort_t*)w;  w += (size_t)Nn * Dd * 2;
    ushort_t* Zh = (ushort_t*)w;  w += (size_t)Nn * Dd * 2;
    ushort_t* Vt = (ushort_t*)w;  w += (size_t)Nn * Dd * 2;
    ushort_t* S  = (ushort_t*)w;  w += (size_t)Nn * Nn * 2;
    float*    PM = (float*)w;     w += (size_t)32 * Nn * 4;
    float*    PS = (float*)w;     w += (size_t)32 * Nn * 4;
    float*    Sc = (float*)w;

    // prep with nx=0: Mt + wkbq + Wvt only
    prep_kernel<<<dim3(1344), 256, 0, stream>>>(
        nullptr, nullptr, 0, Wq, Wk, Wv, (__half*)Wvt, bq, wkbq, (__half*)Mt);

    for (int b = 0; b < Bb; ++b) {
      const float* Xb = X + (long)b * Nn * Dd;
      cvt_f32_f16_kernel<<<dim3((unsigned)((long)Nn * Dd / (8 * 256))), 256, 0, stream>>>(
          Xb, (__half*)Xh, (long)Nn * Dd);
      zv_gemm_kernel<<<dim3(2 * Dd / 128, Nn / 128), 256, 0, stream>>>(
          Xh, MtWvt, wkbq, bv, (__half*)Zh, Vt);
      qk_gemm_kernel<<<dim3(Nn / 128, Nn / 128, 1), 256, 0, stream>>>(
          Zh, Xh, (__half*)S, PM, PS);
      softmax_reduce_kernel<<<dim3(Nn / 256), 256, 0, stream>>>(PM, PS, Sc);
      pv_gemm_kernel<<<dim3(Dd / 128, Nn / 128, 1), 256, 0, stream>>>(
          S, Vt, Sc, Out + (long)b * Nn * Dd);
    }
  }
}